// Round 1
// baseline (45852.786 us; speedup 1.0000x reference)
//
#include <hip/hip_runtime.h>
#include <cstdint>

#define GB_M 128
#define GB_N 64
#define GB_K 16

// C[m,n] = act( sum_k A[row(m),k]*B[n,k] + bias[n] )
// A rows remapped: rc -> (rc>>tc_shift)*Tfull + t0 + (rc & mask)  (chunked time slices)
__global__ __launch_bounds__(256) void gemm_bt_f32(
    const float* __restrict__ A, const float* __restrict__ B,
    const float* __restrict__ bias, float* __restrict__ C,
    int Mc, int N, int K, int tc_shift, int Tfull, int t0, int act)
{
  __shared__ float As[GB_K][GB_M + 4];
  __shared__ float Bs[GB_K][GB_N + 4];
  const int tid = threadIdx.x;
  const int m0 = blockIdx.y * GB_M;
  const int n0 = blockIdx.x * GB_N;
  const int tx = tid & 15;   // n direction (4 each)
  const int ty = tid >> 4;   // m direction (8 each)

  const int tcmask = (1 << tc_shift) - 1;
  int arow[2];
#pragma unroll
  for (int i = 0; i < 2; i++) {
    int f = tid + i * 256;
    int row = f >> 2;
    int rc = m0 + row;
    arow[i] = (rc >> tc_shift) * Tfull + t0 + (rc & tcmask);
  }
  const int akq = tid & 3;
  const int brow = tid >> 2;
  const int bn = n0 + brow;

  float acc[8][4];
#pragma unroll
  for (int i = 0; i < 8; i++)
#pragma unroll
    for (int j = 0; j < 4; j++) acc[i][j] = 0.f;

  for (int k0 = 0; k0 < K; k0 += GB_K) {
#pragma unroll
    for (int i = 0; i < 2; i++) {
      int f = tid + i * 256;
      int row = f >> 2;
      float4 v = *(const float4*)(A + (size_t)arow[i] * K + k0 + akq * 4);
      As[akq * 4 + 0][row] = v.x; As[akq * 4 + 1][row] = v.y;
      As[akq * 4 + 2][row] = v.z; As[akq * 4 + 3][row] = v.w;
    }
    {
      float4 v = make_float4(0.f, 0.f, 0.f, 0.f);
      if (bn < N) v = *(const float4*)(B + (size_t)bn * K + k0 + akq * 4);
      Bs[akq * 4 + 0][brow] = v.x; Bs[akq * 4 + 1][brow] = v.y;
      Bs[akq * 4 + 2][brow] = v.z; Bs[akq * 4 + 3][brow] = v.w;
    }
    __syncthreads();
#pragma unroll
    for (int k = 0; k < GB_K; k++) {
      float4 a0 = *(const float4*)&As[k][ty * 8];
      float4 a1 = *(const float4*)&As[k][ty * 8 + 4];
      float4 b0 = *(const float4*)&Bs[k][tx * 4];
      float av[8] = {a0.x, a0.y, a0.z, a0.w, a1.x, a1.y, a1.z, a1.w};
      float bv[4] = {b0.x, b0.y, b0.z, b0.w};
#pragma unroll
      for (int i = 0; i < 8; i++)
#pragma unroll
        for (int j = 0; j < 4; j++) acc[i][j] += av[i] * bv[j];
    }
    __syncthreads();
  }

#pragma unroll
  for (int j = 0; j < 4; j++) {
    int n = n0 + tx * 4 + j;
    if (n >= N) continue;
    float bz = bias[n];
#pragma unroll
    for (int i = 0; i < 8; i++) {
      int m = m0 + ty * 8 + i;
      float x = acc[i][j] + bz;
      if (act == 1) {
        // SELU
        x = 1.0507009873554805f * (x > 0.f ? x : 1.6732632423543772f * (__expf(x) - 1.f));
      } else if (act == 2) {
        x = tanhf(x);
      }
      C[(size_t)m * N + n] = x;
    }
  }
}

#define RT 384
#define RNWG 256

__device__ __forceinline__ void grid_barrier(unsigned* cnt, unsigned* gen_ptr,
                                             unsigned* gen_local, unsigned nwg)
{
  __syncthreads();
  if (threadIdx.x == 0) {
    __threadfence();  // make h_new visible device-wide
    unsigned arrived = __hip_atomic_fetch_add(cnt, 1u, __ATOMIC_ACQ_REL, __HIP_MEMORY_SCOPE_AGENT);
    if (arrived == nwg - 1u) {
      __hip_atomic_store(cnt, 0u, __ATOMIC_RELAXED, __HIP_MEMORY_SCOPE_AGENT);
      __hip_atomic_store(gen_ptr, *gen_local + 1u, __ATOMIC_RELEASE, __HIP_MEMORY_SCOPE_AGENT);
    } else {
      while (__hip_atomic_load(gen_ptr, __ATOMIC_RELAXED, __HIP_MEMORY_SCOPE_AGENT) == *gen_local) {
        __builtin_amdgcn_s_sleep(2);
      }
      __threadfence();  // acquire: invalidate stale cached h
    }
    (*gen_local)++;
  }
  __syncthreads();
}

// Persistent GRU recurrence over a time-chunk. Grid = 256 WGs (1/CU guaranteed by LDS),
// WG = (jg 0..63, bg 0..3): owns 12 hidden cols j (3 gate rows each, LDS-resident W) x 8 batches.
// Thread = (jl 0..11, bp 0..3, ks 0..7): 3 gate dots x 2 batches, 1/8 of K (interleaved),
// shuffle-reduced over ks.
__global__ __launch_bounds__(RT, 1) void gru_rec(
    const float* __restrict__ gi, const float* __restrict__ w_hh,
    const float* __restrict__ b_hh, float* __restrict__ hbuf,
    unsigned* __restrict__ bar, float* __restrict__ seq,
    int t0, int Tc)
{
  __shared__ float Wl[36][776];   // stride 776: +8 floats pad -> 2-way-max bank aliasing
  __shared__ float hs[8][776];
  const int wg = blockIdx.x;
  const int jg = wg & 63;
  const int bg = wg >> 6;
  const int j0 = jg * 12;
  const int b0 = bg * 8;
  const int tid = threadIdx.x;

  // Load W slice: row l = gate*12 + jl  <->  w_hh[gate*768 + j0 + jl]
  for (int f = tid; f < 36 * 192; f += RT) {
    int row = f / 192;
    int kq = f - row * 192;
    int gate = row / 12;
    int jl = row - gate * 12;
    float4 v = *(const float4*)(w_hh + (size_t)(gate * 768 + j0 + jl) * 768 + kq * 4);
    *(float4*)&Wl[row][kq * 4] = v;
  }

  const int tile = tid >> 3;
  const int ks = tid & 7;
  const int jl = tile >> 2;
  const int bp = tile & 3;
  const int j = j0 + jl;

  const float bhr = b_hh[j];
  const float bhz = b_hh[768 + j];
  const float bhn = b_hh[1536 + j];

  const float* wrp = &Wl[jl][0];
  const float* wzp = &Wl[12 + jl][0];
  const float* wnp = &Wl[24 + jl][0];
  const float* h0p = &hs[2 * bp][0];
  const float* h1p = &hs[2 * bp + 1][0];

  unsigned gen = 0;
  int cur = 0;

  for (int tt = 0; tt < Tc; tt++) {
    const int t = t0 + tt;
    // stage h (8 batches x 768) from global ping buffer into LDS
#pragma unroll
    for (int i = 0; i < 4; i++) {
      int f = tid + i * RT;
      int bi = f / 192;
      int kq = f - bi * 192;
      *(float4*)&hs[bi][kq * 4] =
          *(const float4*)(hbuf + (size_t)cur * 24576 + (size_t)(b0 + bi) * 768 + kq * 4);
    }
    // prefetch gi early so HBM latency hides under the k-loop
    float gr0 = 0.f, gz0 = 0.f, gn0 = 0.f, gr1 = 0.f, gz1 = 0.f, gn1 = 0.f;
    if (ks == 0) {
      const float* g0 = gi + ((size_t)(b0 + 2 * bp) * Tc + tt) * 2304 + j;
      const float* g1 = gi + ((size_t)(b0 + 2 * bp + 1) * Tc + tt) * 2304 + j;
      gr0 = g0[0]; gz0 = g0[768]; gn0 = g0[1536];
      gr1 = g1[0]; gz1 = g1[768]; gn1 = g1[1536];
    }
    __syncthreads();

    float ar0 = 0, az0 = 0, an0 = 0, ar1 = 0, az1 = 0, an1 = 0;
#pragma unroll 4
    for (int kk = 0; kk < 24; kk++) {
      int q = (kk * 8 + ks) * 4;   // interleaved k-split: ks changes bank group
      float4 h0 = *(const float4*)(h0p + q);
      float4 h1 = *(const float4*)(h1p + q);
      float4 wr = *(const float4*)(wrp + q);
      float4 wz = *(const float4*)(wzp + q);
      float4 wn = *(const float4*)(wnp + q);
      ar0 += wr.x * h0.x + wr.y * h0.y + wr.z * h0.z + wr.w * h0.w;
      az0 += wz.x * h0.x + wz.y * h0.y + wz.z * h0.z + wz.w * h0.w;
      an0 += wn.x * h0.x + wn.y * h0.y + wn.z * h0.z + wn.w * h0.w;
      ar1 += wr.x * h1.x + wr.y * h1.y + wr.z * h1.z + wr.w * h1.w;
      az1 += wz.x * h1.x + wz.y * h1.y + wz.z * h1.z + wz.w * h1.w;
      an1 += wn.x * h1.x + wn.y * h1.y + wn.z * h1.z + wn.w * h1.w;
    }
#define RED(x) x += __shfl_xor(x, 1); x += __shfl_xor(x, 2); x += __shfl_xor(x, 4);
    RED(ar0) RED(az0) RED(an0) RED(ar1) RED(az1) RED(an1)
#undef RED

    if (ks == 0) {
      float* hnext = hbuf + (size_t)(cur ^ 1) * 24576;
      {
        int b = b0 + 2 * bp;
        float r = 1.f / (1.f + __expf(-(gr0 + ar0 + bhr)));
        float z = 1.f / (1.f + __expf(-(gz0 + az0 + bhz)));
        float n = tanhf(gn0 + r * (an0 + bhn));
        float hp = h0p[j];
        float hv = (1.f - z) * n + z * hp;
        hnext[(size_t)b * 768 + j] = hv;
        seq[((size_t)b * 1024 + t) * 768 + j] = hv;
      }
      {
        int b = b0 + 2 * bp + 1;
        float r = 1.f / (1.f + __expf(-(gr1 + ar1 + bhr)));
        float z = 1.f / (1.f + __expf(-(gz1 + az1 + bhz)));
        float n = tanhf(gn1 + r * (an1 + bhn));
        float hp = h1p[j];
        float hv = (1.f - z) * n + z * hp;
        hnext[(size_t)b * 768 + j] = hv;
        seq[((size_t)b * 1024 + t) * 768 + j] = hv;
      }
    }
    grid_barrier(bar, bar + 32, &gen, RNWG);
    cur ^= 1;
  }
}

extern "C" void kernel_launch(void* const* d_in, const int* in_sizes, int n_in,
                              void* d_out, int out_size, void* d_ws, size_t ws_size,
                              hipStream_t stream) {
  const float* feat  = (const float*)d_in[0];
  // d_in[1] = padding_mask (unused by forward math)
  const float* w_ih0 = (const float*)d_in[2];
  const float* w_hh0 = (const float*)d_in[3];
  const float* b_ih0 = (const float*)d_in[4];
  const float* b_hh0 = (const float*)d_in[5];
  const float* w_ih1 = (const float*)d_in[6];
  const float* w_hh1 = (const float*)d_in[7];
  const float* b_ih1 = (const float*)d_in[8];
  const float* b_hh1 = (const float*)d_in[9];
  const float* fc_w  = (const float*)d_in[10];
  const float* fc_b  = (const float*)d_in[11];
  const float* out_w = (const float*)d_in[12];
  const float* out_b = (const float*)d_in[13];
  float* out = (float*)d_out;

  const int Tc = 256;              // time chunk (4 chunks)
  const int McChunk = 32 * Tc;     // 8192 rows per chunk GEMM

  float* proj = (float*)d_ws;                          // 32*256*2304 = 18,874,368 f
  float* seq  = proj + (size_t)32 * Tc * 2304;         // 25,165,824 f
  float* hbuf = seq + (size_t)25165824;                // 2 * 32*768 = 49,152 f
  unsigned* bar = (unsigned*)(hbuf + 49152);           // 256 B barrier region

  // ---- layer 0 ----
  hipMemsetAsync(hbuf, 0, 49152 * sizeof(float), stream);
  for (int c = 0; c < 4; c++) {
    gemm_bt_f32<<<dim3(36, McChunk / 128), dim3(256), 0, stream>>>(
        feat, w_ih0, b_ih0, proj, McChunk, 2304, 768, 8, 1024, c * Tc, 0);
    hipMemsetAsync(bar, 0, 256, stream);
    gru_rec<<<dim3(RNWG), dim3(RT), 0, stream>>>(
        proj, w_hh0, b_hh0, hbuf, bar, seq, c * Tc, Tc);
  }
  // ---- layer 1 (in-place: gemm(c) reads seq chunk c before rec(c) overwrites it) ----
  hipMemsetAsync(hbuf, 0, 49152 * sizeof(float), stream);
  for (int c = 0; c < 4; c++) {
    gemm_bt_f32<<<dim3(36, McChunk / 128), dim3(256), 0, stream>>>(
        seq, w_ih1, b_ih1, proj, McChunk, 2304, 768, 8, 1024, c * Tc, 0);
    hipMemsetAsync(bar, 0, 256, stream);
    gru_rec<<<dim3(RNWG), dim3(RT), 0, stream>>>(
        proj, w_hh1, b_hh1, hbuf, bar, seq, c * Tc, Tc);
  }
  // ---- fc + SELU: [32768,768] @ [512,768]^T -> proj (reused) ----
  gemm_bt_f32<<<dim3(8, 256), dim3(256), 0, stream>>>(
      seq, fc_w, fc_b, proj, 32768, 512, 768, 15, 32768, 0, 1);
  // ---- out + tanh: [32768,512] @ [39,512]^T -> d_out ----
  gemm_bt_f32<<<dim3(1, 256), dim3(256), 0, stream>>>(
      proj, out_w, out_b, out, 32768, 39, 512, 15, 32768, 0, 2);
}

// Round 2
// 22361.156 us; speedup vs baseline: 2.0506x; 2.0506x over previous
//
#include <hip/hip_runtime.h>
#include <cstdint>

#define GB_M 128
#define GB_N 64
#define GB_K 16

// C[m,n] = act( sum_k A[row(m),k]*B[n,k] + bias[n] )
// A rows remapped: rc -> (rc>>tc_shift)*Tfull + t0 + (rc & mask)  (chunked time slices)
__global__ __launch_bounds__(256) void gemm_bt_f32(
    const float* __restrict__ A, const float* __restrict__ B,
    const float* __restrict__ bias, float* __restrict__ C,
    int Mc, int N, int K, int tc_shift, int Tfull, int t0, int act)
{
  __shared__ float As[GB_K][GB_M + 4];
  __shared__ float Bs[GB_K][GB_N + 4];
  const int tid = threadIdx.x;
  const int m0 = blockIdx.y * GB_M;
  const int n0 = blockIdx.x * GB_N;
  const int tx = tid & 15;   // n direction (4 each)
  const int ty = tid >> 4;   // m direction (8 each)

  const int tcmask = (1 << tc_shift) - 1;
  int arow[2];
#pragma unroll
  for (int i = 0; i < 2; i++) {
    int f = tid + i * 256;
    int row = f >> 2;
    int rc = m0 + row;
    arow[i] = (rc >> tc_shift) * Tfull + t0 + (rc & tcmask);
  }
  const int akq = tid & 3;
  const int brow = tid >> 2;
  const int bn = n0 + brow;

  float acc[8][4];
#pragma unroll
  for (int i = 0; i < 8; i++)
#pragma unroll
    for (int j = 0; j < 4; j++) acc[i][j] = 0.f;

  for (int k0 = 0; k0 < K; k0 += GB_K) {
#pragma unroll
    for (int i = 0; i < 2; i++) {
      int f = tid + i * 256;
      int row = f >> 2;
      float4 v = *(const float4*)(A + (size_t)arow[i] * K + k0 + akq * 4);
      As[akq * 4 + 0][row] = v.x; As[akq * 4 + 1][row] = v.y;
      As[akq * 4 + 2][row] = v.z; As[akq * 4 + 3][row] = v.w;
    }
    {
      float4 v = make_float4(0.f, 0.f, 0.f, 0.f);
      if (bn < N) v = *(const float4*)(B + (size_t)bn * K + k0 + akq * 4);
      Bs[akq * 4 + 0][brow] = v.x; Bs[akq * 4 + 1][brow] = v.y;
      Bs[akq * 4 + 2][brow] = v.z; Bs[akq * 4 + 3][brow] = v.w;
    }
    __syncthreads();
#pragma unroll
    for (int k = 0; k < GB_K; k++) {
      float4 a0 = *(const float4*)&As[k][ty * 8];
      float4 a1 = *(const float4*)&As[k][ty * 8 + 4];
      float4 b0 = *(const float4*)&Bs[k][tx * 4];
      float av[8] = {a0.x, a0.y, a0.z, a0.w, a1.x, a1.y, a1.z, a1.w};
      float bv[4] = {b0.x, b0.y, b0.z, b0.w};
#pragma unroll
      for (int i = 0; i < 8; i++)
#pragma unroll
        for (int j = 0; j < 4; j++) acc[i][j] += av[i] * bv[j];
    }
    __syncthreads();
  }

#pragma unroll
  for (int j = 0; j < 4; j++) {
    int n = n0 + tx * 4 + j;
    if (n >= N) continue;
    float bz = bias[n];
#pragma unroll
    for (int i = 0; i < 8; i++) {
      int m = m0 + ty * 8 + i;
      float x = acc[i][j] + bz;
      if (act == 1) {
        // SELU
        x = 1.0507009873554805f * (x > 0.f ? x : 1.6732632423543772f * (__expf(x) - 1.f));
      } else if (act == 2) {
        x = tanhf(x);
      }
      C[(size_t)m * N + n] = x;
    }
  }
}

#define RT 384
#define RNWG 256

// Persistent GRU recurrence over a time-chunk. Grid = 256 WGs (1/CU guaranteed by LDS),
// WG = (jg 0..63, bg 0..3): owns 12 hidden cols j (3 gate rows each, LDS-resident W) x 8 batches.
// Thread = (jl 0..11, bp 0..3, ks 0..7): 3 gate dots x 2 batches, 1/8 of K (interleaved),
// shuffle-reduced over ks.
//
// Sync (round 1 -> 2 change): no central barrier. Batches are independent, so each
// bg-group of 64 WGs is its own sync domain. Each WG publishes flag[jg]=tt+1 (relaxed
// agent store, no RMW) after its h-slice is written with agent-scope atomic stores
// (land at LLC -> no producer-side L2 writeback fence). Consumers poll the 64 flags
// with 64 parallel lanes, then one __threadfence (cache inv) before staging.
// 2 h-slots suffice: flag is set only after this WG finished READING the old slot.
__global__ __launch_bounds__(RT, 1) void gru_rec(
    const float* __restrict__ gi, const float* __restrict__ w_hh,
    const float* __restrict__ b_hh, float* __restrict__ hbuf,
    unsigned* __restrict__ flags, float* __restrict__ seq,
    int t0, int Tc)
{
  __shared__ float Wl[36][776];   // stride 776: +8 floats pad -> 2-way-max bank aliasing
  __shared__ float hs[8][776];
  const int wg = blockIdx.x;
  const int jg = wg & 63;
  const int bg = wg >> 6;
  const int j0 = jg * 12;
  const int b0 = bg * 8;
  const int tid = threadIdx.x;

  unsigned* myflag = flags + (((unsigned)bg << 6) + jg) * 16;      // 64B-strided
  const unsigned* pollbase = flags + ((unsigned)bg << 6) * 16;

  // Load W slice: row l = gate*12 + jl  <->  w_hh[gate*768 + j0 + jl]
  for (int f = tid; f < 36 * 192; f += RT) {
    int row = f / 192;
    int kq = f - row * 192;
    int gate = row / 12;
    int jl = row - gate * 12;
    float4 v = *(const float4*)(w_hh + (size_t)(gate * 768 + j0 + jl) * 768 + kq * 4);
    *(float4*)&Wl[row][kq * 4] = v;
  }

  const int tile = tid >> 3;
  const int ks = tid & 7;
  const int jl = tile >> 2;
  const int bp = tile & 3;
  const int j = j0 + jl;

  const float bhr = b_hh[j];
  const float bhz = b_hh[768 + j];
  const float bhn = b_hh[1536 + j];

  const float* wrp = &Wl[jl][0];
  const float* wzp = &Wl[12 + jl][0];
  const float* wnp = &Wl[24 + jl][0];
  const float* h0p = &hs[2 * bp][0];
  const float* h1p = &hs[2 * bp + 1][0];

  int cur = 0;

  for (int tt = 0; tt < Tc; tt++) {
    const int t = t0 + tt;

    // ---- wait until h(tt) is published by all 64 producers of this bg group ----
    if (tid < 64) {
      const unsigned* fp = pollbase + tid * 16;
      while (__hip_atomic_load(fp, __ATOMIC_RELAXED, __HIP_MEMORY_SCOPE_AGENT) < (unsigned)tt) {
        __builtin_amdgcn_s_sleep(1);
      }
      __threadfence();   // invalidate stale L1/L2 lines of hbuf slot before staging
    }
    __syncthreads();

    // stage h (8 batches x 768) from global ping buffer into LDS
#pragma unroll
    for (int i = 0; i < 4; i++) {
      int f = tid + i * RT;
      int bi = f / 192;
      int kq = f - bi * 192;
      *(float4*)&hs[bi][kq * 4] =
          *(const float4*)(hbuf + (size_t)cur * 24576 + (size_t)(b0 + bi) * 768 + kq * 4);
    }
    // prefetch gi early so HBM latency hides under the k-loop
    float gr0 = 0.f, gz0 = 0.f, gn0 = 0.f, gr1 = 0.f, gz1 = 0.f, gn1 = 0.f;
    if (ks == 0) {
      const float* g0 = gi + ((size_t)(b0 + 2 * bp) * Tc + tt) * 2304 + j;
      const float* g1 = gi + ((size_t)(b0 + 2 * bp + 1) * Tc + tt) * 2304 + j;
      gr0 = g0[0]; gz0 = g0[768]; gn0 = g0[1536];
      gr1 = g1[0]; gz1 = g1[768]; gn1 = g1[1536];
    }
    __syncthreads();

    float ar0 = 0, az0 = 0, an0 = 0, ar1 = 0, az1 = 0, an1 = 0;
#pragma unroll 4
    for (int kk = 0; kk < 24; kk++) {
      int q = (kk * 8 + ks) * 4;   // interleaved k-split: ks changes bank group
      float4 h0 = *(const float4*)(h0p + q);
      float4 h1 = *(const float4*)(h1p + q);
      float4 wr = *(const float4*)(wrp + q);
      float4 wz = *(const float4*)(wzp + q);
      float4 wn = *(const float4*)(wnp + q);
      ar0 += wr.x * h0.x + wr.y * h0.y + wr.z * h0.z + wr.w * h0.w;
      az0 += wz.x * h0.x + wz.y * h0.y + wz.z * h0.z + wz.w * h0.w;
      an0 += wn.x * h0.x + wn.y * h0.y + wn.z * h0.z + wn.w * h0.w;
      ar1 += wr.x * h1.x + wr.y * h1.y + wr.z * h1.z + wr.w * h1.w;
      az1 += wz.x * h1.x + wz.y * h1.y + wz.z * h1.z + wz.w * h1.w;
      an1 += wn.x * h1.x + wn.y * h1.y + wn.z * h1.z + wn.w * h1.w;
    }
#define RED(x) x += __shfl_xor(x, 1); x += __shfl_xor(x, 2); x += __shfl_xor(x, 4);
    RED(ar0) RED(az0) RED(an0) RED(ar1) RED(az1) RED(an1)
#undef RED

    if (ks == 0) {
      float* hnext = hbuf + (size_t)(cur ^ 1) * 24576;
      {
        int b = b0 + 2 * bp;
        float r = 1.f / (1.f + __expf(-(gr0 + ar0 + bhr)));
        float z = 1.f / (1.f + __expf(-(gz0 + az0 + bhz)));
        float n = tanhf(gn0 + r * (an0 + bhn));
        float hp = h0p[j];
        float hv = (1.f - z) * n + z * hp;
        __hip_atomic_store(&hnext[(size_t)b * 768 + j], hv,
                           __ATOMIC_RELAXED, __HIP_MEMORY_SCOPE_AGENT);
        seq[((size_t)b * 1024 + t) * 768 + j] = hv;
      }
      {
        int b = b0 + 2 * bp + 1;
        float r = 1.f / (1.f + __expf(-(gr1 + ar1 + bhr)));
        float z = 1.f / (1.f + __expf(-(gz1 + az1 + bhz)));
        float n = tanhf(gn1 + r * (an1 + bhn));
        float hp = h1p[j];
        float hv = (1.f - z) * n + z * hp;
        __hip_atomic_store(&hnext[(size_t)b * 768 + j], hv,
                           __ATOMIC_RELAXED, __HIP_MEMORY_SCOPE_AGENT);
        seq[((size_t)b * 1024 + t) * 768 + j] = hv;
      }
    }
    // all threads' h stores drained (syncthreads emits s_waitcnt vmcnt(0)) -> publish
    __syncthreads();
    if (tid == 0) {
      __hip_atomic_store(myflag, (unsigned)(tt + 1),
                         __ATOMIC_RELAXED, __HIP_MEMORY_SCOPE_AGENT);
    }
    cur ^= 1;
  }
}

extern "C" void kernel_launch(void* const* d_in, const int* in_sizes, int n_in,
                              void* d_out, int out_size, void* d_ws, size_t ws_size,
                              hipStream_t stream) {
  const float* feat  = (const float*)d_in[0];
  // d_in[1] = padding_mask (unused by forward math)
  const float* w_ih0 = (const float*)d_in[2];
  const float* w_hh0 = (const float*)d_in[3];
  const float* b_ih0 = (const float*)d_in[4];
  const float* b_hh0 = (const float*)d_in[5];
  const float* w_ih1 = (const float*)d_in[6];
  const float* w_hh1 = (const float*)d_in[7];
  const float* b_ih1 = (const float*)d_in[8];
  const float* b_hh1 = (const float*)d_in[9];
  const float* fc_w  = (const float*)d_in[10];
  const float* fc_b  = (const float*)d_in[11];
  const float* out_w = (const float*)d_in[12];
  const float* out_b = (const float*)d_in[13];
  float* out = (float*)d_out;

  const int Tc = 256;              // time chunk (4 chunks)
  const int McChunk = 32 * Tc;     // 8192 rows per chunk GEMM

  float* proj = (float*)d_ws;                          // 32*256*2304 = 18,874,368 f
  float* seq  = proj + (size_t)32 * Tc * 2304;         // 25,165,824 f
  float* hbuf = seq + (size_t)25165824;                // 2 * 32*768 = 49,152 f
  unsigned* flags = (unsigned*)(hbuf + 49152);         // 256 flags x 64B = 16 KB

  // ---- layer 0 ----
  hipMemsetAsync(hbuf, 0, 49152 * sizeof(float), stream);
  for (int c = 0; c < 4; c++) {
    gemm_bt_f32<<<dim3(36, McChunk / 128), dim3(256), 0, stream>>>(
        feat, w_ih0, b_ih0, proj, McChunk, 2304, 768, 8, 1024, c * Tc, 0);
    hipMemsetAsync(flags, 0, 16384, stream);
    gru_rec<<<dim3(RNWG), dim3(RT), 0, stream>>>(
        proj, w_hh0, b_hh0, hbuf, flags, seq, c * Tc, Tc);
  }
  // ---- layer 1 (in-place: gemm(c) reads seq chunk c before rec(c) overwrites it) ----
  hipMemsetAsync(hbuf, 0, 49152 * sizeof(float), stream);
  for (int c = 0; c < 4; c++) {
    gemm_bt_f32<<<dim3(36, McChunk / 128), dim3(256), 0, stream>>>(
        seq, w_ih1, b_ih1, proj, McChunk, 2304, 768, 8, 1024, c * Tc, 0);
    hipMemsetAsync(flags, 0, 16384, stream);
    gru_rec<<<dim3(RNWG), dim3(RT), 0, stream>>>(
        proj, w_hh1, b_hh1, hbuf, flags, seq, c * Tc, Tc);
  }
  // ---- fc + SELU: [32768,768] @ [512,768]^T -> proj (reused) ----
  gemm_bt_f32<<<dim3(8, 256), dim3(256), 0, stream>>>(
      seq, fc_w, fc_b, proj, 32768, 512, 768, 15, 32768, 0, 1);
  // ---- out + tanh: [32768,512] @ [39,512]^T -> d_out ----
  gemm_bt_f32<<<dim3(1, 256), dim3(256), 0, stream>>>(
      proj, out_w, out_b, out, 32768, 39, 512, 15, 32768, 0, 2);
}

// Round 3
// 17568.524 us; speedup vs baseline: 2.6099x; 1.2728x over previous
//
#include <hip/hip_runtime.h>
#include <cstdint>

#define GB_M 128
#define GB_N 64
#define GB_K 16

// C[m,n] = act( sum_k A[row(m),k]*B[n,k] + bias[n] )
__global__ __launch_bounds__(256) void gemm_bt_f32(
    const float* __restrict__ A, const float* __restrict__ B,
    const float* __restrict__ bias, float* __restrict__ C,
    int Mc, int N, int K, int tc_shift, int Tfull, int t0, int act)
{
  __shared__ float As[GB_K][GB_M + 4];
  __shared__ float Bs[GB_K][GB_N + 4];
  const int tid = threadIdx.x;
  const int m0 = blockIdx.y * GB_M;
  const int n0 = blockIdx.x * GB_N;
  const int tx = tid & 15;
  const int ty = tid >> 4;

  const int tcmask = (1 << tc_shift) - 1;
  int arow[2];
#pragma unroll
  for (int i = 0; i < 2; i++) {
    int f = tid + i * 256;
    int row = f >> 2;
    int rc = m0 + row;
    arow[i] = (rc >> tc_shift) * Tfull + t0 + (rc & tcmask);
  }
  const int akq = tid & 3;
  const int brow = tid >> 2;
  const int bn = n0 + brow;

  float acc[8][4];
#pragma unroll
  for (int i = 0; i < 8; i++)
#pragma unroll
    for (int j = 0; j < 4; j++) acc[i][j] = 0.f;

  for (int k0 = 0; k0 < K; k0 += GB_K) {
#pragma unroll
    for (int i = 0; i < 2; i++) {
      int f = tid + i * 256;
      int row = f >> 2;
      float4 v = *(const float4*)(A + (size_t)arow[i] * K + k0 + akq * 4);
      As[akq * 4 + 0][row] = v.x; As[akq * 4 + 1][row] = v.y;
      As[akq * 4 + 2][row] = v.z; As[akq * 4 + 3][row] = v.w;
    }
    {
      float4 v = make_float4(0.f, 0.f, 0.f, 0.f);
      if (bn < N) v = *(const float4*)(B + (size_t)bn * K + k0 + akq * 4);
      Bs[akq * 4 + 0][brow] = v.x; Bs[akq * 4 + 1][brow] = v.y;
      Bs[akq * 4 + 2][brow] = v.z; Bs[akq * 4 + 3][brow] = v.w;
    }
    __syncthreads();
#pragma unroll
    for (int k = 0; k < GB_K; k++) {
      float4 a0 = *(const float4*)&As[k][ty * 8];
      float4 a1 = *(const float4*)&As[k][ty * 8 + 4];
      float4 b0 = *(const float4*)&Bs[k][tx * 4];
      float av[8] = {a0.x, a0.y, a0.z, a0.w, a1.x, a1.y, a1.z, a1.w};
      float bv[4] = {b0.x, b0.y, b0.z, b0.w};
#pragma unroll
      for (int i = 0; i < 8; i++)
#pragma unroll
        for (int j = 0; j < 4; j++) acc[i][j] += av[i] * bv[j];
    }
    __syncthreads();
  }

#pragma unroll
  for (int j = 0; j < 4; j++) {
    int n = n0 + tx * 4 + j;
    if (n >= N) continue;
    float bz = bias[n];
#pragma unroll
    for (int i = 0; i < 8; i++) {
      int m = m0 + ty * 8 + i;
      float x = acc[i][j] + bz;
      if (act == 1) {
        x = 1.0507009873554805f * (x > 0.f ? x : 1.6732632423543772f * (__expf(x) - 1.f));
      } else if (act == 2) {
        x = tanhf(x);
      }
      C[(size_t)m * N + n] = x;
    }
  }
}

#define RT 384
#define RNWG 256

// Persistent GRU recurrence. Grid = 256 WGs (1/CU), WG = (jg 0..63, bg 0..3):
// 12 hidden cols x 8 batches, W slice (36 rows x 768) LDS-resident.
// Thread = (p 0..5, q 0..1, ks 0..31): R=6 rows (2j x 3 gates) x C=4 batches,
// k-split 32 (24 k each). Per 4-k: 10 ds_read_b128 -> 96 FMAs.
// Sync: h published as {tag=t+1 | fp32 bits} u64 via relaxed agent-scope atomic
// stores; consumers poll the tagged data directly (no flags, no threadfence).
// 2 slots ping-pong on t&1; a WG overwrites a slot only after all its reads of
// the predecessor step completed (publish happens-after own staging).
__global__ __launch_bounds__(RT, 1) void gru_rec(
    const float* __restrict__ gi, const float* __restrict__ w_hh,
    const float* __restrict__ b_hh, unsigned long long* __restrict__ hb,
    float* __restrict__ seq, int t0, int Tc)
{
  __shared__ float Wl[36][776];   // +8 pad
  __shared__ float hs[8][776];
  const int wg = blockIdx.x;
  const int jg = wg & 63;
  const int bg = wg >> 6;
  const int j0 = jg * 12;
  const int b0 = bg * 8;
  const int tid = threadIdx.x;

  // Load W slice: LDS row l = gate*12 + jl  <->  w_hh[gate*768 + j0 + jl]
  for (int f = tid; f < 36 * 192; f += RT) {
    int row = f / 192;
    int kq = f - row * 192;
    int gate = row / 12;
    int jl = row - gate * 12;
    float4 v = *(const float4*)(w_hh + (size_t)(gate * 768 + j0 + jl) * 768 + kq * 4);
    *(float4*)&Wl[row][kq * 4] = v;
  }

  const int p  = tid >> 6;         // 0..5
  const int q  = (tid >> 5) & 1;   // 0..1
  const int ks = tid & 31;         // 0..31

  // output assignment (lanes ks<8 write): j2 = ks>>2, c = ks&3
  const int j2l = (ks >> 2) & 1;
  const int cl  = ks & 3;
  const int j_out = j0 + 2 * p + j2l;
  const int b_out = b0 + 4 * q + cl;
  const float bhr = b_hh[j_out];
  const float bhz = b_hh[768 + j_out];
  const float bhn = b_hh[1536 + j_out];

  // k-loop base pointers
  const float* wbase[3][2];
#pragma unroll
  for (int g = 0; g < 3; g++)
#pragma unroll
    for (int j2 = 0; j2 < 2; j2++)
      wbase[g][j2] = &Wl[g * 12 + 2 * p + j2][0];
  const float* hbase[4];
#pragma unroll
  for (int c = 0; c < 4; c++) hbase[c] = &hs[4 * q + c][0];

  // staging assignment: 48 threads per batch, interleaved k (stride 48)
  const int sbi = tid / 48;        // 0..7
  const int sk  = tid - sbi * 48;  // 0..47

  for (int tt = 0; tt < Tc; tt++) {
    const int t = t0 + tt;

    // gi prefetch (issued before poll so LLC latency hides under the wait)
    const float* gp = gi + ((size_t)b_out * Tc + tt) * 2304 + j_out;
    float gr = gp[0], gz = gp[768], gn = gp[1536];

    // ---- stage h(t): poll tagged u64s, write fp32 into LDS ----
    {
      const unsigned long long* hsrc =
          hb + (size_t)(t & 1) * 24576 + (size_t)(b0 + sbi) * 768 + sk;
      unsigned long long v[16];
#pragma unroll
      for (int i = 0; i < 16; i++)
        v[i] = __hip_atomic_load(hsrc + 48 * i, __ATOMIC_RELAXED, __HIP_MEMORY_SCOPE_AGENT);
      const unsigned want = (unsigned)t;
      while (true) {
        bool all = true;
#pragma unroll
        for (int i = 0; i < 16; i++) {
          if ((unsigned)(v[i] >> 32) != want) {
            all = false;
            v[i] = __hip_atomic_load(hsrc + 48 * i, __ATOMIC_RELAXED, __HIP_MEMORY_SCOPE_AGENT);
          }
        }
        if (all) break;
        __builtin_amdgcn_s_sleep(1);
      }
#pragma unroll
      for (int i = 0; i < 16; i++)
        hs[sbi][sk + 48 * i] = __uint_as_float((unsigned)v[i]);
    }
    __syncthreads();

    // ---- k-loop: acc[gate][j2][c], 24 accumulators ----
    float acc[3][2][4];
#pragma unroll
    for (int g = 0; g < 3; g++)
#pragma unroll
      for (int j2 = 0; j2 < 2; j2++)
#pragma unroll
        for (int c = 0; c < 4; c++) acc[g][j2][c] = 0.f;

#pragma unroll
    for (int kk = 0; kk < 6; kk++) {
      const int off = (kk * 32 + ks) * 4;
      float4 h[4];
#pragma unroll
      for (int c = 0; c < 4; c++) h[c] = *(const float4*)(hbase[c] + off);
#pragma unroll
      for (int g = 0; g < 3; g++) {
#pragma unroll
        for (int j2 = 0; j2 < 2; j2++) {
          float4 w = *(const float4*)(wbase[g][j2] + off);
#pragma unroll
          for (int c = 0; c < 4; c++) {
            acc[g][j2][c] += w.x * h[c].x + w.y * h[c].y + w.z * h[c].z + w.w * h[c].w;
          }
        }
      }
    }

    // ---- reduce over ks (32 lanes, butterfly: all lanes end with full sums) ----
#pragma unroll
    for (int g = 0; g < 3; g++)
#pragma unroll
      for (int j2 = 0; j2 < 2; j2++)
#pragma unroll
        for (int c = 0; c < 4; c++) {
          float x = acc[g][j2][c];
          x += __shfl_xor(x, 1);
          x += __shfl_xor(x, 2);
          x += __shfl_xor(x, 4);
          x += __shfl_xor(x, 8);
          x += __shfl_xor(x, 16);
          acc[g][j2][c] = x;
        }

    // ---- output: lanes ks<8 handle (j2l, cl) ----
    if (ks < 8) {
      float ar = acc[0][j2l][cl];
      float az = acc[1][j2l][cl];
      float an = acc[2][j2l][cl];
      float hp = hs[4 * q + cl][j_out];
      float r = 1.f / (1.f + __expf(-(gr + ar + bhr)));
      float z = 1.f / (1.f + __expf(-(gz + az + bhz)));
      float n = tanhf(gn + r * (an + bhn));
      float hv = (1.f - z) * n + z * hp;
      unsigned long long pv =
          ((unsigned long long)(unsigned)(t + 1) << 32) |
          (unsigned long long)__float_as_uint(hv);
      __hip_atomic_store(hb + (size_t)((t + 1) & 1) * 24576 + (size_t)b_out * 768 + j_out,
                         pv, __ATOMIC_RELAXED, __HIP_MEMORY_SCOPE_AGENT);
      seq[((size_t)b_out * 1024 + t) * 768 + j_out] = hv;
    }
    __syncthreads();   // protect hs before next staging overwrites
  }
}

extern "C" void kernel_launch(void* const* d_in, const int* in_sizes, int n_in,
                              void* d_out, int out_size, void* d_ws, size_t ws_size,
                              hipStream_t stream) {
  const float* feat  = (const float*)d_in[0];
  const float* w_ih0 = (const float*)d_in[2];
  const float* w_hh0 = (const float*)d_in[3];
  const float* b_ih0 = (const float*)d_in[4];
  const float* b_hh0 = (const float*)d_in[5];
  const float* w_ih1 = (const float*)d_in[6];
  const float* w_hh1 = (const float*)d_in[7];
  const float* b_ih1 = (const float*)d_in[8];
  const float* b_hh1 = (const float*)d_in[9];
  const float* fc_w  = (const float*)d_in[10];
  const float* fc_b  = (const float*)d_in[11];
  const float* out_w = (const float*)d_in[12];
  const float* out_b = (const float*)d_in[13];
  float* out = (float*)d_out;

  const int Tc = 256;
  const int McChunk = 32 * Tc;

  float* proj = (float*)d_ws;                               // 18,874,368 f
  float* seq  = proj + (size_t)32 * Tc * 2304;              // 25,165,824 f
  unsigned long long* hbuf = (unsigned long long*)(seq + 25165824);  // 2*32*768 u64

  // ---- layer 0 ----
  hipMemsetAsync(hbuf, 0, 2 * 32 * 768 * sizeof(unsigned long long), stream);
  for (int c = 0; c < 4; c++) {
    gemm_bt_f32<<<dim3(36, McChunk / 128), dim3(256), 0, stream>>>(
        feat, w_ih0, b_ih0, proj, McChunk, 2304, 768, 8, 1024, c * Tc, 0);
    gru_rec<<<dim3(RNWG), dim3(RT), 0, stream>>>(
        proj, w_hh0, b_hh0, hbuf, seq, c * Tc, Tc);
  }
  // ---- layer 1 ----
  hipMemsetAsync(hbuf, 0, 2 * 32 * 768 * sizeof(unsigned long long), stream);
  for (int c = 0; c < 4; c++) {
    gemm_bt_f32<<<dim3(36, McChunk / 128), dim3(256), 0, stream>>>(
        seq, w_ih1, b_ih1, proj, McChunk, 2304, 768, 8, 1024, c * Tc, 0);
    gru_rec<<<dim3(RNWG), dim3(RT), 0, stream>>>(
        proj, w_hh1, b_hh1, hbuf, seq, c * Tc, Tc);
  }
  // ---- fc + SELU ----
  gemm_bt_f32<<<dim3(8, 256), dim3(256), 0, stream>>>(
      seq, fc_w, fc_b, proj, 32768, 512, 768, 15, 32768, 0, 1);
  // ---- out + tanh ----
  gemm_bt_f32<<<dim3(1, 256), dim3(256), 0, stream>>>(
      proj, out_w, out_b, out, 32768, 39, 512, 15, 32768, 0, 2);
}

// Round 4
// 17459.355 us; speedup vs baseline: 2.6263x; 1.0063x over previous
//
#include <hip/hip_runtime.h>
#include <cstdint>

#define GB_M 128
#define GB_N 64
#define GB_K 16

// C[m,n] = act( sum_k A[row(m),k]*B[n,k] + bias[n] )
__global__ __launch_bounds__(256) void gemm_bt_f32(
    const float* __restrict__ A, const float* __restrict__ B,
    const float* __restrict__ bias, float* __restrict__ C,
    int Mc, int N, int K, int tc_shift, int Tfull, int t0, int act)
{
  __shared__ float As[GB_K][GB_M + 4];
  __shared__ float Bs[GB_K][GB_N + 4];
  const int tid = threadIdx.x;
  const int m0 = blockIdx.y * GB_M;
  const int n0 = blockIdx.x * GB_N;
  const int tx = tid & 15;
  const int ty = tid >> 4;

  const int tcmask = (1 << tc_shift) - 1;
  int arow[2];
#pragma unroll
  for (int i = 0; i < 2; i++) {
    int f = tid + i * 256;
    int row = f >> 2;
    int rc = m0 + row;
    arow[i] = (rc >> tc_shift) * Tfull + t0 + (rc & tcmask);
  }
  const int akq = tid & 3;
  const int brow = tid >> 2;
  const int bn = n0 + brow;

  float acc[8][4];
#pragma unroll
  for (int i = 0; i < 8; i++)
#pragma unroll
    for (int j = 0; j < 4; j++) acc[i][j] = 0.f;

  for (int k0 = 0; k0 < K; k0 += GB_K) {
#pragma unroll
    for (int i = 0; i < 2; i++) {
      int f = tid + i * 256;
      int row = f >> 2;
      float4 v = *(const float4*)(A + (size_t)arow[i] * K + k0 + akq * 4);
      As[akq * 4 + 0][row] = v.x; As[akq * 4 + 1][row] = v.y;
      As[akq * 4 + 2][row] = v.z; As[akq * 4 + 3][row] = v.w;
    }
    {
      float4 v = make_float4(0.f, 0.f, 0.f, 0.f);
      if (bn < N) v = *(const float4*)(B + (size_t)bn * K + k0 + akq * 4);
      Bs[akq * 4 + 0][brow] = v.x; Bs[akq * 4 + 1][brow] = v.y;
      Bs[akq * 4 + 2][brow] = v.z; Bs[akq * 4 + 3][brow] = v.w;
    }
    __syncthreads();
#pragma unroll
    for (int k = 0; k < GB_K; k++) {
      float4 a0 = *(const float4*)&As[k][ty * 8];
      float4 a1 = *(const float4*)&As[k][ty * 8 + 4];
      float4 b0 = *(const float4*)&Bs[k][tx * 4];
      float av[8] = {a0.x, a0.y, a0.z, a0.w, a1.x, a1.y, a1.z, a1.w};
      float bv[4] = {b0.x, b0.y, b0.z, b0.w};
#pragma unroll
      for (int i = 0; i < 8; i++)
#pragma unroll
        for (int j = 0; j < 4; j++) acc[i][j] += av[i] * bv[j];
    }
    __syncthreads();
  }

#pragma unroll
  for (int j = 0; j < 4; j++) {
    int n = n0 + tx * 4 + j;
    if (n >= N) continue;
    float bz = bias[n];
#pragma unroll
    for (int i = 0; i < 8; i++) {
      int m = m0 + ty * 8 + i;
      float x = acc[i][j] + bz;
      if (act == 1) {
        x = 1.0507009873554805f * (x > 0.f ? x : 1.6732632423543772f * (__expf(x) - 1.f));
      } else if (act == 2) {
        x = tanhf(x);
      }
      C[(size_t)m * N + n] = x;
    }
  }
}

#define RT 384
#define RNWG 256

// Persistent GRU recurrence. Grid = 256 WGs (1/CU), WG = (jg 0..63, bg 0..3):
// 12 hidden cols x 8 batches, W slice (36 rows x 768) LDS-resident.
// Thread = (p 0..5, q 0..1, ks 0..31): R=6 rows (2j x 3 gates) x C=4 batches.
//
// Sync (round 3 -> 4 change): narrow flag poll instead of tag-in-data.
// Round 3 polled the whole h-slab (12.6 MB LLC traffic per poll round chip-wide,
// on the same lines producers were storing to). Now: producers store h as plain
// fp32 relaxed agent-scope atomics; __syncthreads drains vmcnt(0) (compiler
// emits it before s_barrier), so the stores are LLC-acked before tid0 publishes
// flag[jg]=t+1 (relaxed agent store, own 64B line). Consumers poll only the 64
// flags of their bg-domain (64 lanes, 1 load each), then read h ONCE with
// coalesced agent-scope u64 loads. No threadfence anywhere (agent-scope atomic
// loads bypass stale caches). 2-slot ping-pong on t&1 stays safe: a WG
// publishes step t+1 only after it finished reading step t, and every producer
// of h(t+2) must first see ALL flags >= t+1, which requires this WG's read of
// slot t to be complete.
__global__ __launch_bounds__(RT, 1) void gru_rec(
    const float* __restrict__ gi, const float* __restrict__ w_hh,
    const float* __restrict__ b_hh, float* __restrict__ hb,
    unsigned* __restrict__ flags, float* __restrict__ seq,
    int t0, int Tc)
{
  __shared__ float Wl[36][776];   // +8 pad
  __shared__ float hs[8][776];
  const int wg = blockIdx.x;
  const int jg = wg & 63;
  const int bg = wg >> 6;
  const int j0 = jg * 12;
  const int b0 = bg * 8;
  const int tid = threadIdx.x;

  unsigned* myflag = flags + (((unsigned)bg << 6) + jg) * 16;   // 64B-strided
  const unsigned* pollbase = flags + ((unsigned)bg << 6) * 16;

  // Load W slice: LDS row l = gate*12 + jl  <->  w_hh[gate*768 + j0 + jl]
  for (int f = tid; f < 36 * 192; f += RT) {
    int row = f / 192;
    int kq = f - row * 192;
    int gate = row / 12;
    int jl = row - gate * 12;
    float4 v = *(const float4*)(w_hh + (size_t)(gate * 768 + j0 + jl) * 768 + kq * 4);
    *(float4*)&Wl[row][kq * 4] = v;
  }

  const int p  = tid >> 6;         // 0..5
  const int q  = (tid >> 5) & 1;   // 0..1
  const int ks = tid & 31;         // 0..31

  const int j2l = (ks >> 2) & 1;
  const int cl  = ks & 3;
  const int j_out = j0 + 2 * p + j2l;
  const int b_out = b0 + 4 * q + cl;
  const float bhr = b_hh[j_out];
  const float bhz = b_hh[768 + j_out];
  const float bhn = b_hh[1536 + j_out];

  const float* wbase[3][2];
#pragma unroll
  for (int g = 0; g < 3; g++)
#pragma unroll
    for (int j2 = 0; j2 < 2; j2++)
      wbase[g][j2] = &Wl[g * 12 + 2 * p + j2][0];
  const float* hbase[4];
#pragma unroll
  for (int c = 0; c < 4; c++) hbase[c] = &hs[4 * q + c][0];

  // staging assignment: 48 threads per batch, 16 contiguous floats (8 u64) each
  const int sbi = tid / 48;        // 0..7
  const int sk  = tid - sbi * 48;  // 0..47

  for (int tt = 0; tt < Tc; tt++) {
    const int t = t0 + tt;

    // gi prefetch (only the lanes that use it), issued before the poll
    float gr = 0.f, gz = 0.f, gn = 0.f;
    if (ks < 8) {
      const float* gp = gi + ((size_t)b_out * Tc + tt) * 2304 + j_out;
      gr = gp[0]; gz = gp[768]; gn = gp[1536];
    }

    // ---- narrow poll: 64 flags, one lane each ----
    if (tid < 64) {
      const unsigned* fp = pollbase + tid * 16;
      while (__hip_atomic_load(fp, __ATOMIC_RELAXED, __HIP_MEMORY_SCOPE_AGENT) < (unsigned)t) {
        __builtin_amdgcn_s_sleep(1);
      }
    }
    __syncthreads();

    // ---- stage h(t): coalesced agent-scope u64 loads, once ----
    {
      const unsigned long long* hsrc = (const unsigned long long*)
          (hb + (size_t)(t & 1) * 24576 + (size_t)(b0 + sbi) * 768 + sk * 16);
      float* dst = &hs[sbi][sk * 16];
      unsigned long long v[8];
#pragma unroll
      for (int i = 0; i < 8; i++)
        v[i] = __hip_atomic_load(hsrc + i, __ATOMIC_RELAXED, __HIP_MEMORY_SCOPE_AGENT);
#pragma unroll
      for (int i = 0; i < 8; i++) {
        float2 f2;
        f2.x = __uint_as_float((unsigned)v[i]);
        f2.y = __uint_as_float((unsigned)(v[i] >> 32));
        *(float2*)(dst + 2 * i) = f2;
      }
    }
    __syncthreads();

    // ---- k-loop: acc[gate][j2][c], 24 accumulators ----
    float acc[3][2][4];
#pragma unroll
    for (int g = 0; g < 3; g++)
#pragma unroll
      for (int j2 = 0; j2 < 2; j2++)
#pragma unroll
        for (int c = 0; c < 4; c++) acc[g][j2][c] = 0.f;

#pragma unroll
    for (int kk = 0; kk < 6; kk++) {
      const int off = (kk * 32 + ks) * 4;
      float4 h[4];
#pragma unroll
      for (int c = 0; c < 4; c++) h[c] = *(const float4*)(hbase[c] + off);
#pragma unroll
      for (int g = 0; g < 3; g++) {
#pragma unroll
        for (int j2 = 0; j2 < 2; j2++) {
          float4 w = *(const float4*)(wbase[g][j2] + off);
#pragma unroll
          for (int c = 0; c < 4; c++) {
            acc[g][j2][c] += w.x * h[c].x + w.y * h[c].y + w.z * h[c].z + w.w * h[c].w;
          }
        }
      }
    }

    // ---- butterfly reduce over ks ----
#pragma unroll
    for (int g = 0; g < 3; g++)
#pragma unroll
      for (int j2 = 0; j2 < 2; j2++)
#pragma unroll
        for (int c = 0; c < 4; c++) {
          float x = acc[g][j2][c];
          x += __shfl_xor(x, 1);
          x += __shfl_xor(x, 2);
          x += __shfl_xor(x, 4);
          x += __shfl_xor(x, 8);
          x += __shfl_xor(x, 16);
          acc[g][j2][c] = x;
        }

    // ---- output: lanes ks<8 handle (j2l, cl) ----
    if (ks < 8) {
      float ar = acc[0][j2l][cl];
      float az = acc[1][j2l][cl];
      float an = acc[2][j2l][cl];
      float hp = hs[4 * q + cl][j_out];
      float r = 1.f / (1.f + __expf(-(gr + ar + bhr)));
      float z = 1.f / (1.f + __expf(-(gz + az + bhz)));
      float n = tanhf(gn + r * (an + bhn));
      float hv = (1.f - z) * n + z * hp;
      __hip_atomic_store(hb + (size_t)((t + 1) & 1) * 24576 + (size_t)b_out * 768 + j_out,
                         hv, __ATOMIC_RELAXED, __HIP_MEMORY_SCOPE_AGENT);
      seq[((size_t)b_out * 1024 + t) * 768 + j_out] = hv;
    }
    // barrier: (a) protects hs for next staging, (b) compiler drains vmcnt(0)
    // before s_barrier -> all h stores LLC-acked before flag publish below
    __syncthreads();
    if (tid == 0) {
      __hip_atomic_store(myflag, (unsigned)(t + 1),
                         __ATOMIC_RELAXED, __HIP_MEMORY_SCOPE_AGENT);
    }
  }
}

extern "C" void kernel_launch(void* const* d_in, const int* in_sizes, int n_in,
                              void* d_out, int out_size, void* d_ws, size_t ws_size,
                              hipStream_t stream) {
  const float* feat  = (const float*)d_in[0];
  const float* w_ih0 = (const float*)d_in[2];
  const float* w_hh0 = (const float*)d_in[3];
  const float* b_ih0 = (const float*)d_in[4];
  const float* b_hh0 = (const float*)d_in[5];
  const float* w_ih1 = (const float*)d_in[6];
  const float* w_hh1 = (const float*)d_in[7];
  const float* b_ih1 = (const float*)d_in[8];
  const float* b_hh1 = (const float*)d_in[9];
  const float* fc_w  = (const float*)d_in[10];
  const float* fc_b  = (const float*)d_in[11];
  const float* out_w = (const float*)d_in[12];
  const float* out_b = (const float*)d_in[13];
  float* out = (float*)d_out;

  const int Tc = 256;
  const int McChunk = 32 * Tc;

  float* proj = (float*)d_ws;                               // 18,874,368 f
  float* seq  = proj + (size_t)32 * Tc * 2304;              // 25,165,824 f
  float* hbuf = seq + (size_t)25165824;                     // 2*24576 f
  unsigned* flags = (unsigned*)(hbuf + 2 * 24576);          // 256 x 64B = 16 KB

  // ---- layer 0 ----
  hipMemsetAsync(hbuf, 0, 2 * 24576 * sizeof(float), stream);
  hipMemsetAsync(flags, 0, 16384, stream);
  for (int c = 0; c < 4; c++) {
    gemm_bt_f32<<<dim3(36, McChunk / 128), dim3(256), 0, stream>>>(
        feat, w_ih0, b_ih0, proj, McChunk, 2304, 768, 8, 1024, c * Tc, 0);
    gru_rec<<<dim3(RNWG), dim3(RT), 0, stream>>>(
        proj, w_hh0, b_hh0, hbuf, flags, seq, c * Tc, Tc);
  }
  // ---- layer 1 ----
  hipMemsetAsync(hbuf, 0, 2 * 24576 * sizeof(float), stream);
  hipMemsetAsync(flags, 0, 16384, stream);
  for (int c = 0; c < 4; c++) {
    gemm_bt_f32<<<dim3(36, McChunk / 128), dim3(256), 0, stream>>>(
        seq, w_ih1, b_ih1, proj, McChunk, 2304, 768, 8, 1024, c * Tc, 0);
    gru_rec<<<dim3(RNWG), dim3(RT), 0, stream>>>(
        proj, w_hh1, b_hh1, hbuf, flags, seq, c * Tc, Tc);
  }
  // ---- fc + SELU ----
  gemm_bt_f32<<<dim3(8, 256), dim3(256), 0, stream>>>(
      seq, fc_w, fc_b, proj, 32768, 512, 768, 15, 32768, 0, 1);
  // ---- out + tanh ----
  gemm_bt_f32<<<dim3(1, 256), dim3(256), 0, stream>>>(
      proj, out_w, out_b, out, 32768, 39, 512, 15, 32768, 0, 2);
}

// Round 5
// 15267.207 us; speedup vs baseline: 3.0034x; 1.1436x over previous
//
#include <hip/hip_runtime.h>
#include <cstdint>

#define GB_M 128
#define GB_N 64
#define GB_K 16

// C[m,n] = act( sum_k A[row(m),k]*B[n,k] + bias[n] )
__global__ __launch_bounds__(256) void gemm_bt_f32(
    const float* __restrict__ A, const float* __restrict__ B,
    const float* __restrict__ bias, float* __restrict__ C,
    int Mc, int N, int K, int tc_shift, int Tfull, int t0, int act)
{
  __shared__ float As[GB_K][GB_M + 4];
  __shared__ float Bs[GB_K][GB_N + 4];
  const int tid = threadIdx.x;
  const int m0 = blockIdx.y * GB_M;
  const int n0 = blockIdx.x * GB_N;
  const int tx = tid & 15;
  const int ty = tid >> 4;

  const int tcmask = (1 << tc_shift) - 1;
  int arow[2];
#pragma unroll
  for (int i = 0; i < 2; i++) {
    int f = tid + i * 256;
    int row = f >> 2;
    int rc = m0 + row;
    arow[i] = (rc >> tc_shift) * Tfull + t0 + (rc & tcmask);
  }
  const int akq = tid & 3;
  const int brow = tid >> 2;
  const int bn = n0 + brow;

  float acc[8][4];
#pragma unroll
  for (int i = 0; i < 8; i++)
#pragma unroll
    for (int j = 0; j < 4; j++) acc[i][j] = 0.f;

  for (int k0 = 0; k0 < K; k0 += GB_K) {
#pragma unroll
    for (int i = 0; i < 2; i++) {
      int f = tid + i * 256;
      int row = f >> 2;
      float4 v = *(const float4*)(A + (size_t)arow[i] * K + k0 + akq * 4);
      As[akq * 4 + 0][row] = v.x; As[akq * 4 + 1][row] = v.y;
      As[akq * 4 + 2][row] = v.z; As[akq * 4 + 3][row] = v.w;
    }
    {
      float4 v = make_float4(0.f, 0.f, 0.f, 0.f);
      if (bn < N) v = *(const float4*)(B + (size_t)bn * K + k0 + akq * 4);
      Bs[akq * 4 + 0][brow] = v.x; Bs[akq * 4 + 1][brow] = v.y;
      Bs[akq * 4 + 2][brow] = v.z; Bs[akq * 4 + 3][brow] = v.w;
    }
    __syncthreads();
#pragma unroll
    for (int k = 0; k < GB_K; k++) {
      float4 a0 = *(const float4*)&As[k][ty * 8];
      float4 a1 = *(const float4*)&As[k][ty * 8 + 4];
      float4 b0 = *(const float4*)&Bs[k][tx * 4];
      float av[8] = {a0.x, a0.y, a0.z, a0.w, a1.x, a1.y, a1.z, a1.w};
      float bv[4] = {b0.x, b0.y, b0.z, b0.w};
#pragma unroll
      for (int i = 0; i < 8; i++)
#pragma unroll
        for (int j = 0; j < 4; j++) acc[i][j] += av[i] * bv[j];
    }
    __syncthreads();
  }

#pragma unroll
  for (int j = 0; j < 4; j++) {
    int n = n0 + tx * 4 + j;
    if (n >= N) continue;
    float bz = bias[n];
#pragma unroll
    for (int i = 0; i < 8; i++) {
      int m = m0 + ty * 8 + i;
      float x = acc[i][j] + bz;
      if (act == 1) {
        x = 1.0507009873554805f * (x > 0.f ? x : 1.6732632423543772f * (__expf(x) - 1.f));
      } else if (act == 2) {
        x = tanhf(x);
      }
      C[(size_t)m * N + n] = x;
    }
  }
}

#define RT 384
#define RNWG 256

__device__ __forceinline__ void pollge(const unsigned* fp, unsigned want) {
  while (__hip_atomic_load(fp, __ATOMIC_RELAXED, __HIP_MEMORY_SCOPE_AGENT) < want)
    __builtin_amdgcn_s_sleep(1);
}

// Persistent GRU recurrence, round-5 structure: batch-pair stagger.
// 256 WGs = 4 super-domains (8 batches) x 64 jg (12 hidden cols). Each WG
// handles two independent 4-batch halves X (b 8sd..+3) and Y (b 8sd+4..+7).
// Round r advances BOTH by one step, staggered:
//   pollX(t) stageX BAR1 [pub flagY=t] kloopX outX(t+1)
//   pollY(t) stageY BAR2 [pub flagX=t+1] kloopY outY(t+1)
// X's flags (pub at peers' BAR2 of round r) are polled at round r+1 start,
// ~1.5us of Y-compute later -> LLC propagation off the critical path (and
// vice versa for Y). 2 barriers / 2 steps. hs rows 0-3=X, 4-7=Y are
// hazard-disjoint; each half's barrier protects the other half's buffers.
// Thread = (p=wave 0..5, ks=lane 0..63): R=6 (2j x 3 gates), C=4, k-split 64
// (12 k each): 30 ds_read_b128 + 288 FMA per half. Reduction: fold j2 / c-hi /
// c-lo across xor 4/2/1 (lane ks&7 ends owning its (j2,c)), then full
// butterfly xor 8/16/32: 30 shfl vs 120.
__global__ __launch_bounds__(RT, 1) void gru_rec(
    const float* __restrict__ gi, const float* __restrict__ w_hh,
    const float* __restrict__ b_hh, float* __restrict__ hb,
    unsigned* __restrict__ flags, float* __restrict__ seq,
    int t0, int Tc)
{
  __shared__ float Wl[36][776];   // +8 pad
  __shared__ float hs[8][776];    // rows 0-3: X batches, 4-7: Y batches
  const int wg = blockIdx.x;
  const int jg = wg & 63;
  const int sd = wg >> 6;         // super-domain (8 batches)
  const int j0 = jg * 12;
  const int tid = threadIdx.x;
  const int p  = tid >> 6;        // wave 0..5
  const int ks = tid & 63;        // lane

  unsigned* flagX_my = flags + (((0 * 4 + sd) * 64) + jg) * 16;
  unsigned* flagY_my = flags + (((1 * 4 + sd) * 64) + jg) * 16;

  // Load W slice: LDS row l = gate*12 + jl  <->  w_hh[gate*768 + j0 + jl]
  for (int f = tid; f < 36 * 192; f += RT) {
    int row = f / 192;
    int kq = f - row * 192;
    int gate = row / 12;
    int jl = row - gate * 12;
    float4 v = *(const float4*)(w_hh + (size_t)(gate * 768 + j0 + jl) * 768 + kq * 4);
    *(float4*)&Wl[row][kq * 4] = v;
  }

  // output-lane constants (used by lanes ks<8; all lanes hold full sums)
  const int j2l = (ks >> 2) & 1;
  const int cl  = ks & 3;
  const int j_out  = j0 + 2 * p + j2l;
  const int bX_out = 8 * sd + cl;
  const int bY_out = 8 * sd + 4 + cl;
  const float bhr = b_hh[j_out];
  const float bhz = b_hh[768 + j_out];
  const float bhn = b_hh[1536 + j_out];

  const float* wb[3][2];
#pragma unroll
  for (int g = 0; g < 3; g++)
#pragma unroll
    for (int j2 = 0; j2 < 2; j2++)
      wb[g][j2] = &Wl[g * 12 + 2 * p + j2][0];

  // staging: 96 threads per batch-in-half, 8 contiguous floats (4 u64) each
  const int sbi = tid / 96;        // 0..3 batch within half
  const int sk  = tid - sbi * 96;  // 0..95
  const int jgA = (sk * 8) / 12;   // producers covering this 8-float j-range
  const int jgB = (sk * 8 + 7) / 12;
  const unsigned* fXA = flags + ((0 * 4 + sd) * 64 + jgA) * 16;
  const unsigned* fXB = flags + ((0 * 4 + sd) * 64 + jgB) * 16;
  const unsigned* fYA = flags + ((1 * 4 + sd) * 64 + jgA) * 16;
  const unsigned* fYB = flags + ((1 * 4 + sd) * 64 + jgB) * 16;

  const bool hi4 = (ks & 4) != 0;
  const bool hi2 = (ks & 2) != 0;
  const bool hi1 = (ks & 1) != 0;

  for (int tt = 0; tt < Tc; tt++) {
    const int t = t0 + tt;

    // ================= X half =================
    pollge(fXA, (unsigned)t);
    pollge(fXB, (unsigned)t);
    // stage X: batch 8sd+sbi -> hs[sbi]
    {
      const unsigned long long* src = (const unsigned long long*)
          (hb + (size_t)(t & 1) * 24576 + (size_t)(8 * sd + sbi) * 768) + sk * 4;
      unsigned long long v[4];
#pragma unroll
      for (int i = 0; i < 4; i++)
        v[i] = __hip_atomic_load(src + i, __ATOMIC_RELAXED, __HIP_MEMORY_SCOPE_AGENT);
      float* dst = &hs[sbi][sk * 8];
      *(float4*)dst = make_float4(
          __uint_as_float((unsigned)v[0]), __uint_as_float((unsigned)(v[0] >> 32)),
          __uint_as_float((unsigned)v[1]), __uint_as_float((unsigned)(v[1] >> 32)));
      *(float4*)(dst + 4) = make_float4(
          __uint_as_float((unsigned)v[2]), __uint_as_float((unsigned)(v[2] >> 32)),
          __uint_as_float((unsigned)v[3]), __uint_as_float((unsigned)(v[3] >> 32)));
    }
    // gi prefetch for X (after stage loads: youngest in vm queue)
    float gXr = 0.f, gXz = 0.f, gXn = 0.f;
    if (ks < 8) {
      const float* gX = gi + ((size_t)bX_out * Tc + tt) * 2304 + j_out;
      gXr = gX[0]; gXz = gX[768]; gXn = gX[1536];
    }
    __syncthreads();   // BAR1: hs X ready; drains outY(t) stores of prev round
    if (tid == 0)
      __hip_atomic_store(flagY_my, (unsigned)t, __ATOMIC_RELAXED, __HIP_MEMORY_SCOPE_AGENT);

    float r3[3];
    {
      float acc[3][2][4];
#pragma unroll
      for (int g = 0; g < 3; g++)
#pragma unroll
        for (int j2 = 0; j2 < 2; j2++)
#pragma unroll
          for (int c = 0; c < 4; c++) acc[g][j2][c] = 0.f;
#pragma unroll
      for (int kk = 0; kk < 3; kk++) {
        const int off = (kk * 64 + ks) * 4;
        float4 h[4];
#pragma unroll
        for (int c = 0; c < 4; c++) h[c] = *(const float4*)(&hs[c][0] + off);
#pragma unroll
        for (int g = 0; g < 3; g++)
#pragma unroll
          for (int j2 = 0; j2 < 2; j2++) {
            float4 w = *(const float4*)(wb[g][j2] + off);
#pragma unroll
            for (int c = 0; c < 4; c++)
              acc[g][j2][c] += w.x * h[c].x + w.y * h[c].y + w.z * h[c].z + w.w * h[c].w;
          }
      }
      // split-reduce: fold j2 (xor4), c-high (xor2), c-low (xor1)
      float r12[3][4];
#pragma unroll
      for (int g = 0; g < 3; g++)
#pragma unroll
        for (int c = 0; c < 4; c++) {
          float send = hi4 ? acc[g][0][c] : acc[g][1][c];
          float keep = hi4 ? acc[g][1][c] : acc[g][0][c];
          r12[g][c] = keep + __shfl_xor(send, 4);
        }
      float r6[3][2];
#pragma unroll
      for (int g = 0; g < 3; g++)
#pragma unroll
        for (int c2 = 0; c2 < 2; c2++) {
          float send = hi2 ? r12[g][c2] : r12[g][2 + c2];
          float keep = hi2 ? r12[g][2 + c2] : r12[g][c2];
          r6[g][c2] = keep + __shfl_xor(send, 2);
        }
#pragma unroll
      for (int g = 0; g < 3; g++) {
        float send = hi1 ? r6[g][0] : r6[g][1];
        float keep = hi1 ? r6[g][1] : r6[g][0];
        r3[g] = keep + __shfl_xor(send, 1);
      }
#pragma unroll
      for (int g = 0; g < 3; g++) {
        r3[g] += __shfl_xor(r3[g], 8);
        r3[g] += __shfl_xor(r3[g], 16);
        r3[g] += __shfl_xor(r3[g], 32);
      }
    }
    if (ks < 8) {
      float hp = hs[cl][j_out];
      float r = 1.f / (1.f + __expf(-(gXr + r3[0] + bhr)));
      float z = 1.f / (1.f + __expf(-(gXz + r3[1] + bhz)));
      float n = tanhf(gXn + r * (r3[2] + bhn));
      float hv = (1.f - z) * n + z * hp;
      __hip_atomic_store(hb + (size_t)((t + 1) & 1) * 24576 + (size_t)bX_out * 768 + j_out,
                         hv, __ATOMIC_RELAXED, __HIP_MEMORY_SCOPE_AGENT);
      seq[((size_t)bX_out * 1024 + t) * 768 + j_out] = hv;
    }

    // ================= Y half =================
    pollge(fYA, (unsigned)t);
    pollge(fYB, (unsigned)t);
    {
      const unsigned long long* src = (const unsigned long long*)
          (hb + (size_t)(t & 1) * 24576 + (size_t)(8 * sd + 4 + sbi) * 768) + sk * 4;
      unsigned long long v[4];
#pragma unroll
      for (int i = 0; i < 4; i++)
        v[i] = __hip_atomic_load(src + i, __ATOMIC_RELAXED, __HIP_MEMORY_SCOPE_AGENT);
      float* dst = &hs[4 + sbi][sk * 8];
      *(float4*)dst = make_float4(
          __uint_as_float((unsigned)v[0]), __uint_as_float((unsigned)(v[0] >> 32)),
          __uint_as_float((unsigned)v[1]), __uint_as_float((unsigned)(v[1] >> 32)));
      *(float4*)(dst + 4) = make_float4(
          __uint_as_float((unsigned)v[2]), __uint_as_float((unsigned)(v[2] >> 32)),
          __uint_as_float((unsigned)v[3]), __uint_as_float((unsigned)(v[3] >> 32)));
    }
    float gYr = 0.f, gYz = 0.f, gYn = 0.f;
    if (ks < 8) {
      const float* gY = gi + ((size_t)bY_out * Tc + tt) * 2304 + j_out;
      gYr = gY[0]; gYz = gY[768]; gYn = gY[1536];
    }
    __syncthreads();   // BAR2: hs Y ready; drains outX(t+1) stores
    if (tid == 0)
      __hip_atomic_store(flagX_my, (unsigned)(t + 1), __ATOMIC_RELAXED, __HIP_MEMORY_SCOPE_AGENT);

    {
      float acc[3][2][4];
#pragma unroll
      for (int g = 0; g < 3; g++)
#pragma unroll
        for (int j2 = 0; j2 < 2; j2++)
#pragma unroll
          for (int c = 0; c < 4; c++) acc[g][j2][c] = 0.f;
#pragma unroll
      for (int kk = 0; kk < 3; kk++) {
        const int off = (kk * 64 + ks) * 4;
        float4 h[4];
#pragma unroll
        for (int c = 0; c < 4; c++) h[c] = *(const float4*)(&hs[4 + c][0] + off);
#pragma unroll
        for (int g = 0; g < 3; g++)
#pragma unroll
          for (int j2 = 0; j2 < 2; j2++) {
            float4 w = *(const float4*)(wb[g][j2] + off);
#pragma unroll
            for (int c = 0; c < 4; c++)
              acc[g][j2][c] += w.x * h[c].x + w.y * h[c].y + w.z * h[c].z + w.w * h[c].w;
          }
      }
      float r12[3][4];
#pragma unroll
      for (int g = 0; g < 3; g++)
#pragma unroll
        for (int c = 0; c < 4; c++) {
          float send = hi4 ? acc[g][0][c] : acc[g][1][c];
          float keep = hi4 ? acc[g][1][c] : acc[g][0][c];
          r12[g][c] = keep + __shfl_xor(send, 4);
        }
      float r6[3][2];
#pragma unroll
      for (int g = 0; g < 3; g++)
#pragma unroll
        for (int c2 = 0; c2 < 2; c2++) {
          float send = hi2 ? r12[g][c2] : r12[g][2 + c2];
          float keep = hi2 ? r12[g][2 + c2] : r12[g][c2];
          r6[g][c2] = keep + __shfl_xor(send, 2);
        }
#pragma unroll
      for (int g = 0; g < 3; g++) {
        float send = hi1 ? r6[g][0] : r6[g][1];
        float keep = hi1 ? r6[g][1] : r6[g][0];
        r3[g] = keep + __shfl_xor(send, 1);
      }
#pragma unroll
      for (int g = 0; g < 3; g++) {
        r3[g] += __shfl_xor(r3[g], 8);
        r3[g] += __shfl_xor(r3[g], 16);
        r3[g] += __shfl_xor(r3[g], 32);
      }
    }
    if (ks < 8) {
      float hp = hs[4 + cl][j_out];
      float r = 1.f / (1.f + __expf(-(gYr + r3[0] + bhr)));
      float z = 1.f / (1.f + __expf(-(gYz + r3[1] + bhz)));
      float n = tanhf(gYn + r * (r3[2] + bhn));
      float hv = (1.f - z) * n + z * hp;
      __hip_atomic_store(hb + (size_t)((t + 1) & 1) * 24576 + (size_t)bY_out * 768 + j_out,
                         hv, __ATOMIC_RELAXED, __HIP_MEMORY_SCOPE_AGENT);
      seq[((size_t)bY_out * 1024 + t) * 768 + j_out] = hv;
    }
  }
  // tail: publish Y's final step so the next dispatch can start
  __syncthreads();
  if (tid == 0)
    __hip_atomic_store(flagY_my, (unsigned)(t0 + Tc), __ATOMIC_RELAXED, __HIP_MEMORY_SCOPE_AGENT);
}

extern "C" void kernel_launch(void* const* d_in, const int* in_sizes, int n_in,
                              void* d_out, int out_size, void* d_ws, size_t ws_size,
                              hipStream_t stream) {
  const float* feat  = (const float*)d_in[0];
  const float* w_ih0 = (const float*)d_in[2];
  const float* w_hh0 = (const float*)d_in[3];
  const float* b_ih0 = (const float*)d_in[4];
  const float* b_hh0 = (const float*)d_in[5];
  const float* w_ih1 = (const float*)d_in[6];
  const float* w_hh1 = (const float*)d_in[7];
  const float* b_ih1 = (const float*)d_in[8];
  const float* b_hh1 = (const float*)d_in[9];
  const float* fc_w  = (const float*)d_in[10];
  const float* fc_b  = (const float*)d_in[11];
  const float* out_w = (const float*)d_in[12];
  const float* out_b = (const float*)d_in[13];
  float* out = (float*)d_out;

  const int Tc = 256;
  const int McChunk = 32 * Tc;

  float* proj = (float*)d_ws;                               // 18,874,368 f
  float* seq  = proj + (size_t)32 * Tc * 2304;              // 25,165,824 f
  float* hbuf = seq + (size_t)25165824;                     // 2*24576 f
  unsigned* flags = (unsigned*)(hbuf + 2 * 24576);          // 2 x 256 x 64B = 32 KB

  // ---- layer 0 ----
  hipMemsetAsync(hbuf, 0, 2 * 24576 * sizeof(float), stream);
  hipMemsetAsync(flags, 0, 32768, stream);
  for (int c = 0; c < 4; c++) {
    gemm_bt_f32<<<dim3(36, McChunk / 128), dim3(256), 0, stream>>>(
        feat, w_ih0, b_ih0, proj, McChunk, 2304, 768, 8, 1024, c * Tc, 0);
    gru_rec<<<dim3(RNWG), dim3(RT), 0, stream>>>(
        proj, w_hh0, b_hh0, hbuf, flags, seq, c * Tc, Tc);
  }
  // ---- layer 1 ----
  hipMemsetAsync(hbuf, 0, 2 * 24576 * sizeof(float), stream);
  hipMemsetAsync(flags, 0, 32768, stream);
  for (int c = 0; c < 4; c++) {
    gemm_bt_f32<<<dim3(36, McChunk / 128), dim3(256), 0, stream>>>(
        seq, w_ih1, b_ih1, proj, McChunk, 2304, 768, 8, 1024, c * Tc, 0);
    gru_rec<<<dim3(RNWG), dim3(RT), 0, stream>>>(
        proj, w_hh1, b_hh1, hbuf, flags, seq, c * Tc, Tc);
  }
  // ---- fc + SELU ----
  gemm_bt_f32<<<dim3(8, 256), dim3(256), 0, stream>>>(
      seq, fc_w, fc_b, proj, 32768, 512, 768, 15, 32768, 0, 1);
  // ---- out + tanh ----
  gemm_bt_f32<<<dim3(1, 256), dim3(256), 0, stream>>>(
      proj, out_w, out_b, out, 32768, 39, 512, 15, 32768, 0, 2);
}

// Round 6
// 14063.255 us; speedup vs baseline: 3.2605x; 1.0856x over previous
//
#include <hip/hip_runtime.h>
#include <cstdint>

typedef float vf2 __attribute__((ext_vector_type(2)));

#define GB_M 128
#define GB_N 64
#define GB_K 16

// C[m,n] = act( sum_k A[row(m),k]*B[n,k] + bias[n] )
__global__ __launch_bounds__(256) void gemm_bt_f32(
    const float* __restrict__ A, const float* __restrict__ B,
    const float* __restrict__ bias, float* __restrict__ C,
    int Mc, int N, int K, int tc_shift, int Tfull, int t0, int act)
{
  __shared__ float As[GB_K][GB_M + 4];
  __shared__ float Bs[GB_K][GB_N + 4];
  const int tid = threadIdx.x;
  const int m0 = blockIdx.y * GB_M;
  const int n0 = blockIdx.x * GB_N;
  const int tx = tid & 15;
  const int ty = tid >> 4;

  const int tcmask = (1 << tc_shift) - 1;
  int arow[2];
#pragma unroll
  for (int i = 0; i < 2; i++) {
    int f = tid + i * 256;
    int row = f >> 2;
    int rc = m0 + row;
    arow[i] = (rc >> tc_shift) * Tfull + t0 + (rc & tcmask);
  }
  const int akq = tid & 3;
  const int brow = tid >> 2;
  const int bn = n0 + brow;

  float acc[8][4];
#pragma unroll
  for (int i = 0; i < 8; i++)
#pragma unroll
    for (int j = 0; j < 4; j++) acc[i][j] = 0.f;

  for (int k0 = 0; k0 < K; k0 += GB_K) {
#pragma unroll
    for (int i = 0; i < 2; i++) {
      int f = tid + i * 256;
      int row = f >> 2;
      float4 v = *(const float4*)(A + (size_t)arow[i] * K + k0 + akq * 4);
      As[akq * 4 + 0][row] = v.x; As[akq * 4 + 1][row] = v.y;
      As[akq * 4 + 2][row] = v.z; As[akq * 4 + 3][row] = v.w;
    }
    {
      float4 v = make_float4(0.f, 0.f, 0.f, 0.f);
      if (bn < N) v = *(const float4*)(B + (size_t)bn * K + k0 + akq * 4);
      Bs[akq * 4 + 0][brow] = v.x; Bs[akq * 4 + 1][brow] = v.y;
      Bs[akq * 4 + 2][brow] = v.z; Bs[akq * 4 + 3][brow] = v.w;
    }
    __syncthreads();
#pragma unroll
    for (int k = 0; k < GB_K; k++) {
      float4 a0 = *(const float4*)&As[k][ty * 8];
      float4 a1 = *(const float4*)&As[k][ty * 8 + 4];
      float4 b0 = *(const float4*)&Bs[k][tx * 4];
      float av[8] = {a0.x, a0.y, a0.z, a0.w, a1.x, a1.y, a1.z, a1.w};
      float bv[4] = {b0.x, b0.y, b0.z, b0.w};
#pragma unroll
      for (int i = 0; i < 8; i++)
#pragma unroll
        for (int j = 0; j < 4; j++) acc[i][j] += av[i] * bv[j];
    }
    __syncthreads();
  }

#pragma unroll
  for (int j = 0; j < 4; j++) {
    int n = n0 + tx * 4 + j;
    if (n >= N) continue;
    float bz = bias[n];
#pragma unroll
    for (int i = 0; i < 8; i++) {
      int m = m0 + ty * 8 + i;
      float x = acc[i][j] + bz;
      if (act == 1) {
        x = 1.0507009873554805f * (x > 0.f ? x : 1.6732632423543772f * (__expf(x) - 1.f));
      } else if (act == 2) {
        x = tanhf(x);
      }
      C[(size_t)m * N + n] = x;
    }
  }
}

#define RT 384
#define RNWG 256

__device__ __forceinline__ void pollge(const unsigned* fp, unsigned want) {
  while (__hip_atomic_load(fp, __ATOMIC_RELAXED, __HIP_MEMORY_SCOPE_AGENT) < want)
    __builtin_amdgcn_s_sleep(1);
}

// Persistent GRU recurrence, round-6: r5's batch-pair stagger + W-in-registers
// + packed fp32 FMA.
// 256 WGs = 4 super-domains (8 batches) x 64 jg (12 hidden cols). Each WG:
// halves X (b 8sd..+3) / Y (8sd+4..+7), staggered; 2 barriers / 2 steps;
// flags publish after the barrier's vmcnt(0) drain (unchanged from r5).
// W: each thread's 6 rows x 12 k-floats (same for X and Y) = 18 float4 in
// VGPRs, loaded coalesced from global once. K-loop reads only h from LDS
// (12 ds_read_b128 per half). Accumulate in float2 (v_pk_fma_f32).
// Dummy 64 KB dynamic LDS keeps allocation >80 KB -> 1 WG/CU (co-residency).
__global__ __launch_bounds__(RT, 1) void gru_rec(
    const float* __restrict__ gi, const float* __restrict__ w_hh,
    const float* __restrict__ b_hh, float* __restrict__ hb,
    unsigned* __restrict__ flags, float* __restrict__ seq,
    int t0, int Tc)
{
  __shared__ float hs[8][776];    // rows 0-3: X batches, 4-7: Y batches
  const int wg = blockIdx.x;
  const int jg = wg & 63;
  const int sd = wg >> 6;
  const int j0 = jg * 12;
  const int tid = threadIdx.x;
  const int p  = tid >> 6;        // wave 0..5
  const int ks = tid & 63;        // lane

  unsigned* flagX_my = flags + (((0 * 4 + sd) * 64) + jg) * 16;
  unsigned* flagY_my = flags + (((1 * 4 + sd) * 64) + jg) * 16;

  // ---- W slice into registers: [g][j2][kk], row g*768+j0+2p+j2, 16B at (kk*64+ks)*4
  float4 wreg[3][2][3];
#pragma unroll
  for (int g = 0; g < 3; g++)
#pragma unroll
    for (int j2 = 0; j2 < 2; j2++)
#pragma unroll
      for (int kk = 0; kk < 3; kk++)
        wreg[g][j2][kk] = *(const float4*)(
            w_hh + (size_t)(g * 768 + j0 + 2 * p + j2) * 768 + (kk * 64 + ks) * 4);

  const int j2l = (ks >> 2) & 1;
  const int cl  = ks & 3;
  const int j_out  = j0 + 2 * p + j2l;
  const int bX_out = 8 * sd + cl;
  const int bY_out = 8 * sd + 4 + cl;
  const float bhr = b_hh[j_out];
  const float bhz = b_hh[768 + j_out];
  const float bhn = b_hh[1536 + j_out];

  // staging: 96 threads per batch-in-half, 8 contiguous floats (4 u64) each
  const int sbi = tid / 96;
  const int sk  = tid - sbi * 96;
  const int jgA = (sk * 8) / 12;
  const int jgB = (sk * 8 + 7) / 12;
  const unsigned* fXA = flags + ((0 * 4 + sd) * 64 + jgA) * 16;
  const unsigned* fXB = flags + ((0 * 4 + sd) * 64 + jgB) * 16;
  const unsigned* fYA = flags + ((1 * 4 + sd) * 64 + jgA) * 16;
  const unsigned* fYB = flags + ((1 * 4 + sd) * 64 + jgB) * 16;

  const bool hi4 = (ks & 4) != 0;
  const bool hi2 = (ks & 2) != 0;
  const bool hi1 = (ks & 1) != 0;

  for (int tt = 0; tt < Tc; tt++) {
    const int t = t0 + tt;

    // ================= X half =================
    pollge(fXA, (unsigned)t);
    pollge(fXB, (unsigned)t);
    {
      const unsigned long long* src = (const unsigned long long*)
          (hb + (size_t)(t & 1) * 24576 + (size_t)(8 * sd + sbi) * 768) + sk * 4;
      unsigned long long v[4];
#pragma unroll
      for (int i = 0; i < 4; i++)
        v[i] = __hip_atomic_load(src + i, __ATOMIC_RELAXED, __HIP_MEMORY_SCOPE_AGENT);
      float* dst = &hs[sbi][sk * 8];
      *(float4*)dst = make_float4(
          __uint_as_float((unsigned)v[0]), __uint_as_float((unsigned)(v[0] >> 32)),
          __uint_as_float((unsigned)v[1]), __uint_as_float((unsigned)(v[1] >> 32)));
      *(float4*)(dst + 4) = make_float4(
          __uint_as_float((unsigned)v[2]), __uint_as_float((unsigned)(v[2] >> 32)),
          __uint_as_float((unsigned)v[3]), __uint_as_float((unsigned)(v[3] >> 32)));
    }
    float gXr = 0.f, gXz = 0.f, gXn = 0.f;
    if (ks < 8) {
      const float* gX = gi + ((size_t)bX_out * Tc + tt) * 2304 + j_out;
      gXr = gX[0]; gXz = gX[768]; gXn = gX[1536];
    }
    __syncthreads();   // BAR1: hs X ready; drains outY(t) stores of prev round
    if (tid == 0)
      __hip_atomic_store(flagY_my, (unsigned)t, __ATOMIC_RELAXED, __HIP_MEMORY_SCOPE_AGENT);

    float r3[3];
    {
      vf2 a2[3][2][4];
#pragma unroll
      for (int g = 0; g < 3; g++)
#pragma unroll
        for (int j2 = 0; j2 < 2; j2++)
#pragma unroll
          for (int c = 0; c < 4; c++) a2[g][j2][c] = (vf2)(0.f);
#pragma unroll
      for (int kk = 0; kk < 3; kk++) {
        const int off = (kk * 64 + ks) * 4;
        vf2 hlo[4], hhi[4];
#pragma unroll
        for (int c = 0; c < 4; c++) {
          float4 h = *(const float4*)(&hs[c][0] + off);
          hlo[c] = (vf2){h.x, h.y};
          hhi[c] = (vf2){h.z, h.w};
        }
#pragma unroll
        for (int g = 0; g < 3; g++)
#pragma unroll
          for (int j2 = 0; j2 < 2; j2++) {
            float4 w = wreg[g][j2][kk];
            vf2 wlo = (vf2){w.x, w.y};
            vf2 whi = (vf2){w.z, w.w};
#pragma unroll
            for (int c = 0; c < 4; c++) {
              a2[g][j2][c] = __builtin_elementwise_fma(wlo, hlo[c], a2[g][j2][c]);
              a2[g][j2][c] = __builtin_elementwise_fma(whi, hhi[c], a2[g][j2][c]);
            }
          }
      }
      float acc[3][2][4];
#pragma unroll
      for (int g = 0; g < 3; g++)
#pragma unroll
        for (int j2 = 0; j2 < 2; j2++)
#pragma unroll
          for (int c = 0; c < 4; c++) acc[g][j2][c] = a2[g][j2][c].x + a2[g][j2][c].y;

      float r12[3][4];
#pragma unroll
      for (int g = 0; g < 3; g++)
#pragma unroll
        for (int c = 0; c < 4; c++) {
          float send = hi4 ? acc[g][0][c] : acc[g][1][c];
          float keep = hi4 ? acc[g][1][c] : acc[g][0][c];
          r12[g][c] = keep + __shfl_xor(send, 4);
        }
      float r6[3][2];
#pragma unroll
      for (int g = 0; g < 3; g++)
#pragma unroll
        for (int c2 = 0; c2 < 2; c2++) {
          float send = hi2 ? r12[g][c2] : r12[g][2 + c2];
          float keep = hi2 ? r12[g][2 + c2] : r12[g][c2];
          r6[g][c2] = keep + __shfl_xor(send, 2);
        }
#pragma unroll
      for (int g = 0; g < 3; g++) {
        float send = hi1 ? r6[g][0] : r6[g][1];
        float keep = hi1 ? r6[g][1] : r6[g][0];
        r3[g] = keep + __shfl_xor(send, 1);
      }
#pragma unroll
      for (int g = 0; g < 3; g++) {
        r3[g] += __shfl_xor(r3[g], 8);
        r3[g] += __shfl_xor(r3[g], 16);
        r3[g] += __shfl_xor(r3[g], 32);
      }
    }
    if (ks < 8) {
      float hp = hs[cl][j_out];
      float r = 1.f / (1.f + __expf(-(gXr + r3[0] + bhr)));
      float z = 1.f / (1.f + __expf(-(gXz + r3[1] + bhz)));
      float n = tanhf(gXn + r * (r3[2] + bhn));
      float hv = (1.f - z) * n + z * hp;
      __hip_atomic_store(hb + (size_t)((t + 1) & 1) * 24576 + (size_t)bX_out * 768 + j_out,
                         hv, __ATOMIC_RELAXED, __HIP_MEMORY_SCOPE_AGENT);
      seq[((size_t)bX_out * 1024 + t) * 768 + j_out] = hv;
    }

    // ================= Y half =================
    pollge(fYA, (unsigned)t);
    pollge(fYB, (unsigned)t);
    {
      const unsigned long long* src = (const unsigned long long*)
          (hb + (size_t)(t & 1) * 24576 + (size_t)(8 * sd + 4 + sbi) * 768) + sk * 4;
      unsigned long long v[4];
#pragma unroll
      for (int i = 0; i < 4; i++)
        v[i] = __hip_atomic_load(src + i, __ATOMIC_RELAXED, __HIP_MEMORY_SCOPE_AGENT);
      float* dst = &hs[4 + sbi][sk * 8];
      *(float4*)dst = make_float4(
          __uint_as_float((unsigned)v[0]), __uint_as_float((unsigned)(v[0] >> 32)),
          __uint_as_float((unsigned)v[1]), __uint_as_float((unsigned)(v[1] >> 32)));
      *(float4*)(dst + 4) = make_float4(
          __uint_as_float((unsigned)v[2]), __uint_as_float((unsigned)(v[2] >> 32)),
          __uint_as_float((unsigned)v[3]), __uint_as_float((unsigned)(v[3] >> 32)));
    }
    float gYr = 0.f, gYz = 0.f, gYn = 0.f;
    if (ks < 8) {
      const float* gY = gi + ((size_t)bY_out * Tc + tt) * 2304 + j_out;
      gYr = gY[0]; gYz = gY[768]; gYn = gY[1536];
    }
    __syncthreads();   // BAR2: hs Y ready; drains outX(t+1) stores
    if (tid == 0)
      __hip_atomic_store(flagX_my, (unsigned)(t + 1), __ATOMIC_RELAXED, __HIP_MEMORY_SCOPE_AGENT);

    {
      vf2 a2[3][2][4];
#pragma unroll
      for (int g = 0; g < 3; g++)
#pragma unroll
        for (int j2 = 0; j2 < 2; j2++)
#pragma unroll
          for (int c = 0; c < 4; c++) a2[g][j2][c] = (vf2)(0.f);
#pragma unroll
      for (int kk = 0; kk < 3; kk++) {
        const int off = (kk * 64 + ks) * 4;
        vf2 hlo[4], hhi[4];
#pragma unroll
        for (int c = 0; c < 4; c++) {
          float4 h = *(const float4*)(&hs[4 + c][0] + off);
          hlo[c] = (vf2){h.x, h.y};
          hhi[c] = (vf2){h.z, h.w};
        }
#pragma unroll
        for (int g = 0; g < 3; g++)
#pragma unroll
          for (int j2 = 0; j2 < 2; j2++) {
            float4 w = wreg[g][j2][kk];
            vf2 wlo = (vf2){w.x, w.y};
            vf2 whi = (vf2){w.z, w.w};
#pragma unroll
            for (int c = 0; c < 4; c++) {
              a2[g][j2][c] = __builtin_elementwise_fma(wlo, hlo[c], a2[g][j2][c]);
              a2[g][j2][c] = __builtin_elementwise_fma(whi, hhi[c], a2[g][j2][c]);
            }
          }
      }
      float acc[3][2][4];
#pragma unroll
      for (int g = 0; g < 3; g++)
#pragma unroll
        for (int j2 = 0; j2 < 2; j2++)
#pragma unroll
          for (int c = 0; c < 4; c++) acc[g][j2][c] = a2[g][j2][c].x + a2[g][j2][c].y;

      float r12[3][4];
#pragma unroll
      for (int g = 0; g < 3; g++)
#pragma unroll
        for (int c = 0; c < 4; c++) {
          float send = hi4 ? acc[g][0][c] : acc[g][1][c];
          float keep = hi4 ? acc[g][1][c] : acc[g][0][c];
          r12[g][c] = keep + __shfl_xor(send, 4);
        }
      float r6[3][2];
#pragma unroll
      for (int g = 0; g < 3; g++)
#pragma unroll
        for (int c2 = 0; c2 < 2; c2++) {
          float send = hi2 ? r12[g][c2] : r12[g][2 + c2];
          float keep = hi2 ? r12[g][2 + c2] : r12[g][c2];
          r6[g][c2] = keep + __shfl_xor(send, 2);
        }
#pragma unroll
      for (int g = 0; g < 3; g++) {
        float send = hi1 ? r6[g][0] : r6[g][1];
        float keep = hi1 ? r6[g][1] : r6[g][0];
        r3[g] = keep + __shfl_xor(send, 1);
      }
#pragma unroll
      for (int g = 0; g < 3; g++) {
        r3[g] += __shfl_xor(r3[g], 8);
        r3[g] += __shfl_xor(r3[g], 16);
        r3[g] += __shfl_xor(r3[g], 32);
      }
    }
    if (ks < 8) {
      float hp = hs[4 + cl][j_out];
      float r = 1.f / (1.f + __expf(-(gYr + r3[0] + bhr)));
      float z = 1.f / (1.f + __expf(-(gYz + r3[1] + bhz)));
      float n = tanhf(gYn + r * (r3[2] + bhn));
      float hv = (1.f - z) * n + z * hp;
      __hip_atomic_store(hb + (size_t)((t + 1) & 1) * 24576 + (size_t)bY_out * 768 + j_out,
                         hv, __ATOMIC_RELAXED, __HIP_MEMORY_SCOPE_AGENT);
      seq[((size_t)bY_out * 1024 + t) * 768 + j_out] = hv;
    }
  }
  // tail: publish Y's final step so the next dispatch can start
  __syncthreads();
  if (tid == 0)
    __hip_atomic_store(flagY_my, (unsigned)(t0 + Tc), __ATOMIC_RELAXED, __HIP_MEMORY_SCOPE_AGENT);
}

extern "C" void kernel_launch(void* const* d_in, const int* in_sizes, int n_in,
                              void* d_out, int out_size, void* d_ws, size_t ws_size,
                              hipStream_t stream) {
  const float* feat  = (const float*)d_in[0];
  const float* w_ih0 = (const float*)d_in[2];
  const float* w_hh0 = (const float*)d_in[3];
  const float* b_ih0 = (const float*)d_in[4];
  const float* b_hh0 = (const float*)d_in[5];
  const float* w_ih1 = (const float*)d_in[6];
  const float* w_hh1 = (const float*)d_in[7];
  const float* b_ih1 = (const float*)d_in[8];
  const float* b_hh1 = (const float*)d_in[9];
  const float* fc_w  = (const float*)d_in[10];
  const float* fc_b  = (const float*)d_in[11];
  const float* out_w = (const float*)d_in[12];
  const float* out_b = (const float*)d_in[13];
  float* out = (float*)d_out;

  const int Tc = 256;
  const int McChunk = 32 * Tc;
  const size_t DYN_LDS = 65536;   // dead dynamic LDS: pins 1 WG/CU (>80 KB total)

  float* proj = (float*)d_ws;                               // 18,874,368 f
  float* seq  = proj + (size_t)32 * Tc * 2304;              // 25,165,824 f
  float* hbuf = seq + (size_t)25165824;                     // 2*24576 f
  unsigned* flags = (unsigned*)(hbuf + 2 * 24576);          // 2 x 256 x 64B = 32 KB

  // ---- layer 0 ----
  hipMemsetAsync(hbuf, 0, 2 * 24576 * sizeof(float), stream);
  hipMemsetAsync(flags, 0, 32768, stream);
  for (int c = 0; c < 4; c++) {
    gemm_bt_f32<<<dim3(36, McChunk / 128), dim3(256), 0, stream>>>(
        feat, w_ih0, b_ih0, proj, McChunk, 2304, 768, 8, 1024, c * Tc, 0);
    gru_rec<<<dim3(RNWG), dim3(RT), DYN_LDS, stream>>>(
        proj, w_hh0, b_hh0, hbuf, flags, seq, c * Tc, Tc);
  }
  // ---- layer 1 ----
  hipMemsetAsync(hbuf, 0, 2 * 24576 * sizeof(float), stream);
  hipMemsetAsync(flags, 0, 32768, stream);
  for (int c = 0; c < 4; c++) {
    gemm_bt_f32<<<dim3(36, McChunk / 128), dim3(256), 0, stream>>>(
        seq, w_ih1, b_ih1, proj, McChunk, 2304, 768, 8, 1024, c * Tc, 0);
    gru_rec<<<dim3(RNWG), dim3(RT), DYN_LDS, stream>>>(
        proj, w_hh1, b_hh1, hbuf, flags, seq, c * Tc, Tc);
  }
  // ---- fc + SELU ----
  gemm_bt_f32<<<dim3(8, 256), dim3(256), 0, stream>>>(
      seq, fc_w, fc_b, proj, 32768, 512, 768, 15, 32768, 0, 1);
  // ---- out + tanh ----
  gemm_bt_f32<<<dim3(1, 256), dim3(256), 0, stream>>>(
      proj, out_w, out_b, out, 32768, 39, 512, 15, 32768, 0, 2);
}